// Round 18
// baseline (386.506 us; speedup 1.0000x reference)
//
#include <hip/hip_runtime.h>
#include <stdint.h>

typedef __attribute__((ext_vector_type(4))) float f32x4;
typedef __attribute__((ext_vector_type(8))) __bf16 bf16x8;
typedef __attribute__((ext_vector_type(4))) uint16_t u16x4;

#define CDIM 1024
#define LSEQ 13
#define NTOK 4096
#define NHEAD 16

__device__ __forceinline__ uint16_t f2bf(float x){
  union { float f; uint32_t u; } c; c.f = x;
  uint32_t r = (c.u + 0x7FFFu + ((c.u >> 16) & 1u)) >> 16;
  return (uint16_t)r;
}
__device__ __forceinline__ float bf2f(uint16_t h){
  union { uint32_t u; float f; } c; c.u = ((uint32_t)h) << 16;
  return c.f;
}

__device__ __forceinline__ void async16(const void* g, void* l){
  __builtin_amdgcn_global_load_lds((__attribute__((address_space(1))) void*)(g),
                                   (__attribute__((address_space(3))) void*)(l), 16, 0, 0);
}

// ---------------- conversion kernels ----------------

// all four weight matrices in one dispatch; blockIdx.y selects the matrix
__global__ void convert_W4(const float* __restrict__ Wq, const float* __restrict__ Wk,
                           const float* __restrict__ Wv, const float* __restrict__ Wo,
                           uint16_t* __restrict__ W1q, uint16_t* __restrict__ W1k,
                           uint16_t* __restrict__ W1v, uint16_t* __restrict__ W1o){
  const float* W = (blockIdx.y == 0) ? Wq : (blockIdx.y == 1) ? Wk : (blockIdx.y == 2) ? Wv : Wo;
  uint16_t* W1   = (blockIdx.y == 0) ? W1q : (blockIdx.y == 1) ? W1k : (blockIdx.y == 2) ? W1v : W1o;
  int idx = blockIdx.x * 256 + threadIdx.x;
  int j = idx >> 8;
  int c4 = (idx & 255) * 4;
  float4 v = *(const float4*)(W + (size_t)j * CDIM + c4);
  u16x4 h;
  h.x = f2bf(v.x); h.y = f2bf(v.y); h.z = f2bf(v.z); h.w = f2bf(v.w);
  *(u16x4*)(W1 + (size_t)j * CDIM + c4) = h;
}

__global__ void rope_table(float* __restrict__ cosT, float* __restrict__ sinT){
  int t = threadIdx.x;
  if (t < LSEQ * 32){
    int l = t >> 5, i = t & 31;
    float inv = 1.0f / powf(10000.0f, ((float)(2 * i)) / 64.0f);
    float a = (float)l * inv;
    cosT[t] = cosf(a);
    sinT[t] = sinf(a);
  }
}

// chunk A rows (n_local*13 + l) -> bf16 hi
__global__ void convert_A(const float* __restrict__ src, uint16_t* __restrict__ Ah, int n0){
  int idx = blockIdx.x * 256 + threadIdx.x;
  int row = idx >> 8;
  int c4 = (idx & 255) * 4;
  int nl = row / 13;
  int l  = row - nl * 13;
  float4 v = *(const float4*)(src + (size_t)l * (NTOK * CDIM) + (size_t)(n0 + nl) * CDIM + c4);
  u16x4 h;
  h.x = f2bf(v.x); h.y = f2bf(v.y); h.z = f2bf(v.z); h.w = f2bf(v.w);
  *(u16x4*)(Ah + (size_t)row * CDIM + c4) = h;
}

// Q input rows (l = 12 only) -> bf16 hi  (multi-chunk fallback only)
__global__ void convert_Aq1(const float* __restrict__ src, uint16_t* __restrict__ Ah){
  int idx = blockIdx.x * 256 + threadIdx.x;
  int n = idx >> 8;
  int c4 = (idx & 255) * 4;
  float4 v = *(const float4*)(src + (size_t)12 * (NTOK * CDIM) + (size_t)n * CDIM + c4);
  u16x4 h;
  h.x = f2bf(v.x); h.y = f2bf(v.y); h.z = f2bf(v.z); h.w = f2bf(v.w);
  *(u16x4*)(Ah + (size_t)n * CDIM + c4) = h;
}

// ---------------- 128x128 x1 GEMM template (2-barrier m97 structure) ----------------
// AMODE 0: A row-major stride CDIM. AMODE 1: A in [head][NTOK][64] planes.
template<int AMODE>
__global__ __launch_bounds__(256, 2)
void gemm128(const uint16_t* __restrict__ Ahi, const uint16_t* __restrict__ B1,
             float* __restrict__ Cout)
{
  __shared__ __align__(16) uint16_t sA[128 * 64];
  __shared__ __align__(16) uint16_t sB[128 * 64];
  const int tid  = threadIdx.x;
  const int lane = tid & 63;
  const int wave = tid >> 6;
  const int arow0 = blockIdx.x * 128;
  const int bcol0 = blockIdx.y * 128;
  const int wr = (wave >> 1) * 64;
  const int wc = (wave & 1) * 64;

  const f32x4 fzero = {0.f, 0.f, 0.f, 0.f};
  f32x4 acc[4][4];
#pragma unroll
  for (int i = 0; i < 4; ++i)
#pragma unroll
    for (int j = 0; j < 4; ++j)
      acc[i][j] = fzero;

  size_t aOff[4], bOff[4];
  int ldsOff[4];
#pragma unroll
  for (int i = 0; i < 4; ++i){
    int o = i * 256 + tid;
    int row = o >> 3;
    int ss = (o & 7) ^ (row & 7);
    if (AMODE == 1) aOff[i] = (size_t)(arow0 + row) * 64 + ss * 8;
    else            aOff[i] = (size_t)(arow0 + row) * CDIM + ss * 8;
    bOff[i] = (size_t)(bcol0 + row) * CDIM + ss * 8;
    ldsOff[i] = (i * 256 + wave * 64) * 16;
  }

  int aRd[2][4], bRd[2][4];
#pragma unroll
  for (int ks = 0; ks < 2; ++ks){
    int sw = ((lane >> 4) + ks * 4) ^ (lane & 7);
#pragma unroll
    for (int mi = 0; mi < 4; ++mi){
      aRd[ks][mi] = (wr + mi * 16 + (lane & 15)) * 128 + sw * 16;
      bRd[ks][mi] = (wc + mi * 16 + (lane & 15)) * 128 + sw * 16;
    }
  }

  const char* sAc = (const char*)sA;
  const char* sBc = (const char*)sB;

  for (int step = 0; step < 16; ++step){
    const int kr0 = step * 64;
    const size_t aStep = (AMODE == 1) ? ((size_t)(kr0 >> 6) * (NTOK * 64)) : (size_t)kr0;
#pragma unroll
    for (int i = 0; i < 4; ++i){
      async16(Ahi + aStep + aOff[i], (char*)sA + ldsOff[i]);
      async16(B1 + bOff[i] + kr0, (char*)sB + ldsOff[i]);
    }
    __syncthreads();
#pragma unroll
    for (int ks = 0; ks < 2; ++ks){
      bf16x8 af[4], bfr[4];
#pragma unroll
      for (int mi = 0; mi < 4; ++mi) af[mi]  = *(const bf16x8*)(sAc + aRd[ks][mi]);
#pragma unroll
      for (int ni = 0; ni < 4; ++ni) bfr[ni] = *(const bf16x8*)(sBc + bRd[ks][ni]);
#pragma unroll
      for (int mi = 0; mi < 4; ++mi)
#pragma unroll
        for (int ni = 0; ni < 4; ++ni)
          acc[mi][ni] = __builtin_amdgcn_mfma_f32_16x16x32_bf16(af[mi], bfr[ni], acc[mi][ni], 0, 0, 0);
    }
    __syncthreads();
  }

#pragma unroll
  for (int mi = 0; mi < 4; ++mi){
    const int row = arow0 + wr + mi * 16 + (lane >> 4) * 4;
#pragma unroll
    for (int r = 0; r < 4; ++r){
      float* crow = Cout + (size_t)(row + r) * CDIM + bcol0 + wc + (lane & 15);
#pragma unroll
      for (int ni = 0; ni < 4; ++ni)
        crow[ni * 16] = acc[mi][ni][r];
    }
  }
}

// ---------------- 256x256 8-phase x1 GEMM — fused K projection + Q projection ----------------
__global__ __launch_bounds__(512, 1)
void gemm8_kq(const uint16_t* __restrict__ Ahi, const uint16_t* __restrict__ Bk,
              const uint16_t* __restrict__ Bq, uint16_t* __restrict__ Kout,
              float* __restrict__ Qout, int mtK)
{
  constexpr int NSTEP = 16;
  __shared__ __align__(16) char smem[131072];
  const int tid  = threadIdx.x;
  const int lane = tid & 63;
  const int wave = tid >> 6;
  const int wave_m = wave >> 2;
  const int wave_n = wave & 3;
  const bool isQ = (int)blockIdx.y >= mtK;
  const int arow0 = (isQ ? ((int)blockIdx.y - mtK) : (int)blockIdx.y) * 256;
  const int bcol0 = blockIdx.x * 256;
  const uint16_t* B1 = isQ ? Bq : Bk;

  const f32x4 fzero = {0.f, 0.f, 0.f, 0.f};
  f32x4 acc[8][4];
#pragma unroll
  for (int i = 0; i < 8; ++i)
#pragma unroll
    for (int j = 0; j < 4; ++j)
      acc[i][j] = fzero;

  const int abase0 = (wave_m * 128 + (lane & 15)) * 128;
  const int bbase0 = (wave_n * 64  + (lane & 15)) * 128;
  const int s0 = (((lane >> 4))     ^ (lane & 7)) * 16;
  const int s1 = ((4 + (lane >> 4)) ^ (lane & 7)) * 16;

  size_t aU[2][2], bU[2][2];
  int ldsU[2][2];
#pragma unroll
  for (int h = 0; h < 2; ++h)
#pragma unroll
    for (int j = 0; j < 2; ++j){
      int u = h * 1024 + (wave * 2 + j) * 64 + lane;
      int row = u >> 3;
      int ss = (u & 7) ^ (row & 7);          // pre-swizzled source slot (rule #21)
      aU[h][j] = isQ ? (((size_t)(arow0 + row) * 13 + 12) * CDIM + ss * 8)
                     : ((size_t)(arow0 + row) * CDIM + ss * 8);
      bU[h][j] = (size_t)(bcol0 + row) * CDIM + ss * 8;
      ldsU[h][j] = (h * 1024 + (wave * 2 + j) * 64) * 16;
    }

  auto stA = [&](int h, int tt, int dsel){
    const int k0 = tt * 64;
    async16(Ahi + aU[h][0] + k0, smem + dsel + ldsU[h][0]);
    async16(Ahi + aU[h][1] + k0, smem + dsel + ldsU[h][1]);
  };
  auto stB = [&](int h, int tt, int dsel){
    const int k0 = tt * 64;
    async16(B1 + bU[h][0] + k0, smem + 65536 + dsel + ldsU[h][0]);
    async16(B1 + bU[h][1] + k0, smem + 65536 + dsel + ldsU[h][1]);
  };

#define RDA(dst, M, As) { dst[0] = *(const bf16x8*)((As) + abase0 + (M)*2048 + s0); \
                          dst[1] = *(const bf16x8*)((As) + abase0 + (M)*2048 + s1); }
#define MM(MI, AF) { _Pragma("unroll") for (int n = 0; n < 4; ++n){ \
    acc[MI][n] = __builtin_amdgcn_mfma_f32_16x16x32_bf16(AF[0], bf[n][0], acc[MI][n], 0, 0, 0); \
    acc[MI][n] = __builtin_amdgcn_mfma_f32_16x16x32_bf16(AF[1], bf[n][1], acc[MI][n], 0, 0, 0); } }

  // prologue
  stB(0, 0, 0);     stB(1, 0, 0);     stA(0, 0, 0);     stA(1, 0, 0);
  stB(0, 1, 32768); stB(1, 1, 32768); stA(0, 1, 32768);
  asm volatile("s_waitcnt vmcnt(6)" ::: "memory");
  __builtin_amdgcn_sched_barrier(0);
  __builtin_amdgcn_s_barrier();

#pragma unroll 2
  for (int t = 0; t < NSTEP; ++t){
    const int sel  = (t & 1) * 32768;
    const int seln = 32768 - sel;
    const char* As = smem + sel;
    const char* Bs = smem + 65536 + sel;

    bf16x8 bf[4][2], a0[2], a1[2], a2[2], a3[2], a4[2], a5[2], a6[2], a7[2];

    // phase 0
#pragma unroll
    for (int n = 0; n < 4; ++n){
      bf[n][0] = *(const bf16x8*)(Bs + bbase0 + n * 2048 + s0);
      bf[n][1] = *(const bf16x8*)(Bs + bbase0 + n * 2048 + s1);
    }
    RDA(a0, 0, As); RDA(a1, 1, As);
    if (t + 1 < NSTEP) stA(1, t + 1, seln);
    __builtin_amdgcn_s_barrier();
    __builtin_amdgcn_s_setprio(1);
    MM(0, a0); MM(1, a1);
    __builtin_amdgcn_s_setprio(0);
    __builtin_amdgcn_s_barrier();

    // phase 1
    RDA(a2, 2, As); RDA(a3, 3, As); RDA(a4, 4, As); RDA(a5, 5, As);
    if (t + 2 < NSTEP) stB(0, t + 2, sel);
    __builtin_amdgcn_s_barrier();
    __builtin_amdgcn_s_setprio(1);
    MM(2, a2); MM(3, a3);
    __builtin_amdgcn_s_setprio(0);
    __builtin_amdgcn_s_barrier();

    // phase 2
    RDA(a6, 6, As); RDA(a7, 7, As);
    if (t + 2 < NSTEP) stB(1, t + 2, sel);
    __builtin_amdgcn_s_barrier();
    __builtin_amdgcn_s_setprio(1);
    MM(4, a4); MM(5, a5);
    __builtin_amdgcn_s_setprio(0);
    asm volatile("s_waitcnt lgkmcnt(0)" ::: "memory");
    __builtin_amdgcn_sched_barrier(0);
    __builtin_amdgcn_s_barrier();

    // phase 3
    if (t + 2 < NSTEP) stA(0, t + 2, sel);
    if (t <= NSTEP - 3) { asm volatile("s_waitcnt vmcnt(6)" ::: "memory"); }
    else                { asm volatile("s_waitcnt vmcnt(0)" ::: "memory"); }
    __builtin_amdgcn_sched_barrier(0);
    __builtin_amdgcn_s_barrier();
    __builtin_amdgcn_s_setprio(1);
    MM(6, a6); MM(7, a7);
    __builtin_amdgcn_s_setprio(0);
    __builtin_amdgcn_s_barrier();
  }
#undef RDA
#undef MM

#pragma unroll
  for (int mi = 0; mi < 8; ++mi){
    const int row = arow0 + wave_m * 128 + mi * 16 + (lane >> 4) * 4;
#pragma unroll
    for (int r = 0; r < 4; ++r){
      const size_t co = (size_t)(row + r) * CDIM + bcol0 + wave_n * 64 + (lane & 15);
      if (isQ){
        float* crow = Qout + co;
#pragma unroll
        for (int ni = 0; ni < 4; ++ni)
          crow[ni * 16] = acc[mi][ni][r];
      } else {
        uint16_t* crow = Kout + co;
#pragma unroll
        for (int ni = 0; ni < 4; ++ni)
          crow[ni * 16] = f2bf(acc[mi][ni][r]);
      }
    }
  }
}

// ---------------- fused RoPE scores + mix: MIX[h][n][c] = sum_m p[m] * seq[n,m,c] ----------------
// Phase 1 (wave = head): scores -> sP[13][16].
// Phase 2 (head-quartet x column-quad): thread j owns cols (j&255)*4..+3 for heads
// (j>>8)*4..+3: u16x4 LDS reads (8B/lane), wave-uniform sP broadcast, u16x4 stores.
__global__ __launch_bounds__(1024)
void attnmix(const uint16_t* __restrict__ Kb, const uint16_t* __restrict__ Ah,
             const float* __restrict__ q, const float* __restrict__ cosT,
             const float* __restrict__ sinT, uint16_t* __restrict__ MIX, int n0)
{
  __shared__ __align__(16) uint16_t sSeq[LSEQ * CDIM];   // 26 KB
  __shared__ __align__(16) float sP[LSEQ][NHEAD];
  const int tid  = threadIdx.x;
  const int lane = tid & 63;
  const int h    = tid >> 6;
  const int nl   = blockIdx.x;
  const int n    = n0 + nl;
  const int d = lane, i = d & 31;

  const uint16_t* Abase = Ah + (size_t)nl * (LSEQ * CDIM);
  {
    async16(Abase + (size_t)tid * 8, (char*)sSeq + (tid - lane) * 16);
    int u1 = 1024 + tid;
    if (u1 < LSEQ * 128)
      async16(Abase + (size_t)u1 * 8, (char*)sSeq + (1024 + tid - lane) * 16);
  }

  float qv = q[(size_t)n * CDIM + h * 64 + d];
  float qp = __shfl_xor(qv, 32);
  float cq = cosT[12 * 32 + i], sq = sinT[12 * 32 + i];
  float qr = (d < 32) ? (qv * cq - qp * sq) : (qv * cq + qp * sq);

  const uint16_t* Kp = Kb + (size_t)nl * (LSEQ * CDIM) + h * 64 + d;
  float s[LSEQ];
#pragma unroll
  for (int m = 0; m < LSEQ; ++m){
    float kv = bf2f(Kp[m * CDIM]);
    float kp = __shfl_xor(kv, 32);
    float cm = cosT[m * 32 + i], sm = sinT[m * 32 + i];
    float kr = (d < 32) ? (kv * cm - kp * sm) : (kv * cm + kp * sm);
    float p = qr * kr;
    p += __shfl_xor(p, 32); p += __shfl_xor(p, 16); p += __shfl_xor(p, 8);
    p += __shfl_xor(p, 4);  p += __shfl_xor(p, 2);  p += __shfl_xor(p, 1);
    s[m] = p * 0.125f;
  }
  float mx = s[0];
#pragma unroll
  for (int m = 1; m < LSEQ; ++m) mx = fmaxf(mx, s[m]);
  float sum = 0.f;
#pragma unroll
  for (int m = 0; m < LSEQ; ++m){ s[m] = expf(s[m] - mx); sum += s[m]; }
  float inv = 1.0f / sum;
#pragma unroll
  for (int m = 0; m < LSEQ; ++m) s[m] *= inv;

  if (lane == 0){
#pragma unroll
    for (int m = 0; m < LSEQ; ++m) sP[m][h] = s[m];
  }

  __syncthreads();   // seq staged (drains vmcnt) + sP published

  const int c0 = (tid & 255) * 4;
  const int hq = (tid >> 8) * 4;          // wave-uniform head-quartet base
  float ac[4][4];                          // [head][col]
#pragma unroll
  for (int a = 0; a < 4; ++a)
#pragma unroll
    for (int b = 0; b < 4; ++b) ac[a][b] = 0.f;
#pragma unroll
  for (int m = 0; m < LSEQ; ++m){
    u16x4 v = *(const u16x4*)(sSeq + m * CDIM + c0);
    float f0 = bf2f(v.x), f1 = bf2f(v.y), f2 = bf2f(v.z), f3 = bf2f(v.w);
    const f32x4 pq = *(const f32x4*)&sP[m][hq];
    ac[0][0] += pq.x * f0; ac[0][1] += pq.x * f1; ac[0][2] += pq.x * f2; ac[0][3] += pq.x * f3;
    ac[1][0] += pq.y * f0; ac[1][1] += pq.y * f1; ac[1][2] += pq.y * f2; ac[1][3] += pq.y * f3;
    ac[2][0] += pq.z * f0; ac[2][1] += pq.z * f1; ac[2][2] += pq.z * f2; ac[2][3] += pq.z * f3;
    ac[3][0] += pq.w * f0; ac[3][1] += pq.w * f1; ac[3][2] += pq.w * f2; ac[3][3] += pq.w * f3;
  }
#pragma unroll
  for (int kk = 0; kk < 4; ++kk){
    u16x4 o;
    o.x = f2bf(ac[kk][0]); o.y = f2bf(ac[kk][1]);
    o.z = f2bf(ac[kk][2]); o.w = f2bf(ac[kk][3]);
    *(u16x4*)(MIX + ((size_t)(hq + kk) * NTOK + n) * CDIM + c0) = o;
  }
}

// ---------------- per-head GEMM: t1[h][n][d] = MIX[h][n][:] . Wv[h*64+d][:] (bf16 out) ----------------
__global__ __launch_bounds__(256, 2)
void hd_gemm(const uint16_t* __restrict__ MIX, const uint16_t* __restrict__ Wv,
             uint16_t* __restrict__ t1h)
{
  __shared__ __align__(16) uint16_t sA[256 * 64];
  __shared__ __align__(16) uint16_t sB[64 * 64];
  const int tid  = threadIdx.x;
  const int lane = tid & 63;
  const int wave = tid >> 6;
  const int h     = blockIdx.y;
  const int arow0 = blockIdx.x * 256;
  const uint16_t* Aplane = MIX + (size_t)h * ((size_t)NTOK * CDIM);
  const uint16_t* Bbase  = Wv + (size_t)h * 64 * CDIM;

  const f32x4 fzero = {0.f, 0.f, 0.f, 0.f};
  f32x4 acc[4][4];
#pragma unroll
  for (int i = 0; i < 4; ++i)
#pragma unroll
    for (int j = 0; j < 4; ++j)
      acc[i][j] = fzero;

  size_t aOff[8]; int aLds[8];
#pragma unroll
  for (int i = 0; i < 8; ++i){
    int u = i * 256 + tid;
    int row = u >> 3;
    int ss = (u & 7) ^ (row & 7);
    aOff[i] = (size_t)(arow0 + row) * CDIM + ss * 8;
    aLds[i] = (i * 256 + wave * 64) * 16;
  }
  size_t bOff[2]; int bLds[2];
#pragma unroll
  for (int i = 0; i < 2; ++i){
    int u = i * 256 + tid;
    int row = u >> 3;
    int ss = (u & 7) ^ (row & 7);
    bOff[i] = (size_t)row * CDIM + ss * 8;
    bLds[i] = (i * 256 + wave * 64) * 16;
  }

  int aRd[2][4], bRd[2][4];
#pragma unroll
  for (int ks = 0; ks < 2; ++ks){
    int sw = ((lane >> 4) + ks * 4) ^ (lane & 7);
#pragma unroll
    for (int mi = 0; mi < 4; ++mi){
      aRd[ks][mi] = (wave * 64 + mi * 16 + (lane & 15)) * 128 + sw * 16;
      bRd[ks][mi] = (mi * 16 + (lane & 15)) * 128 + sw * 16;
    }
  }

  const char* sAc = (const char*)sA;
  const char* sBc = (const char*)sB;

  for (int step = 0; step < 16; ++step){
    const int k0 = step * 64;
#pragma unroll
    for (int i = 0; i < 8; ++i)
      async16(Aplane + aOff[i] + k0, (char*)sA + aLds[i]);
#pragma unroll
    for (int i = 0; i < 2; ++i)
      async16(Bbase + bOff[i] + k0, (char*)sB + bLds[i]);
    __syncthreads();
#pragma unroll
    for (int ks = 0; ks < 2; ++ks){
      bf16x8 af[4], bfr[4];
#pragma unroll
      for (int mi = 0; mi < 4; ++mi) af[mi]  = *(const bf16x8*)(sAc + aRd[ks][mi]);
#pragma unroll
      for (int ni = 0; ni < 4; ++ni) bfr[ni] = *(const bf16x8*)(sBc + bRd[ks][ni]);
#pragma unroll
      for (int mi = 0; mi < 4; ++mi)
#pragma unroll
        for (int ni = 0; ni < 4; ++ni)
          acc[mi][ni] = __builtin_amdgcn_mfma_f32_16x16x32_bf16(af[mi], bfr[ni], acc[mi][ni], 0, 0, 0);
    }
    __syncthreads();
  }

#pragma unroll
  for (int mi = 0; mi < 4; ++mi){
    const int row = arow0 + wave * 64 + mi * 16 + (lane >> 4) * 4;
#pragma unroll
    for (int r = 0; r < 4; ++r){
      const size_t base = ((size_t)h * NTOK + row + r) * 64 + (lane & 15);
#pragma unroll
      for (int ni = 0; ni < 4; ++ni)
        t1h[base + ni * 16] = f2bf(acc[mi][ni][r]);
    }
  }
}

// ---------------- host ----------------
extern "C" void kernel_launch(void* const* d_in, const int* in_sizes, int n_in,
                              void* d_out, int out_size, void* d_ws, size_t ws_size,
                              hipStream_t stream)
{
  (void)in_sizes; (void)n_in; (void)out_size;
  const float* src = (const float*)d_in[0];
  const float* Wq  = (const float*)d_in[1];
  const float* Wk  = (const float*)d_in[2];
  const float* Wv  = (const float*)d_in[3];
  const float* Wo  = (const float*)d_in[4];
  float* out = (float*)d_out;

  int cn = 4096;
  while (cn > 256 && (180000000ull + (size_t)cn * 53248ull) > ws_size) cn >>= 1;
  const int nchunks = NTOK / cn;

  char* p = (char*)d_ws;
  auto carve = [&](size_t bytes) -> void* {
    void* r = (void*)p; p += (bytes + 255) & ~(size_t)255; return r;
  };
  uint16_t* W1q = (uint16_t*)carve((size_t)CDIM * CDIM * 2);
  uint16_t* W1k = (uint16_t*)carve((size_t)CDIM * CDIM * 2);
  uint16_t* W1v = (uint16_t*)carve((size_t)CDIM * CDIM * 2);
  uint16_t* W1o = (uint16_t*)carve((size_t)CDIM * CDIM * 2);
  float* cosT = (float*)carve(LSEQ * 32 * 4);
  float* sinT = (float*)carve(LSEQ * 32 * 4);
  uint16_t* Aqh = (uint16_t*)carve((size_t)NTOK * CDIM * 2);   // multi-chunk fallback only
  float* qbuf   = (float*)carve((size_t)NTOK * CDIM * 4);
  uint16_t* MIX = (uint16_t*)carve((size_t)NHEAD * NTOK * CDIM * 2);   // 134 MB
  uint16_t* t1h = (uint16_t*)carve((size_t)NHEAD * NTOK * 64 * 2);
  uint16_t* Ah  = (uint16_t*)carve((size_t)cn * LSEQ * CDIM * 2);
  uint16_t* Kb  = (uint16_t*)carve((size_t)cn * LSEQ * CDIM * 2);

  convert_W4<<<dim3(1024, 4), 256, 0, stream>>>(Wq, Wk, Wv, Wo, W1q, W1k, W1v, W1o);
  rope_table<<<1, 512, 0, stream>>>(cosT, sinT);

  if (nchunks > 1){
    convert_Aq1<<<NTOK, 256, 0, stream>>>(src, Aqh);
    gemm128<0><<<dim3(NTOK / 128, 8), 256, 0, stream>>>(Aqh, W1q, qbuf);
  }

  for (int c = 0; c < nchunks; ++c){
    const int mtK = cn * LSEQ / 256;
    const int mtQ = (nchunks == 1) ? (NTOK / 256) : 0;   // fold Q tiles into the K dispatch
    convert_A<<<cn * LSEQ, 256, 0, stream>>>(src, Ah, c * cn);
    gemm8_kq<<<dim3(4, mtK + mtQ), 512, 0, stream>>>(Ah, W1k, W1q, Kb, qbuf, mtK);
    attnmix<<<cn, 1024, 0, stream>>>(Kb, Ah, qbuf, cosT, sinT, MIX, c * cn);
  }
  hd_gemm<<<dim3(16, 16), 256, 0, stream>>>(MIX, W1v, t1h);
  gemm128<1><<<dim3(NTOK / 128, 8), 256, 0, stream>>>(t1h, W1o, out);
}

// Round 19
// 370.084 us; speedup vs baseline: 1.0444x; 1.0444x over previous
//
#include <hip/hip_runtime.h>
#include <stdint.h>

typedef __attribute__((ext_vector_type(4))) float f32x4;
typedef __attribute__((ext_vector_type(8))) __bf16 bf16x8;
typedef __attribute__((ext_vector_type(4))) uint16_t u16x4;

#define CDIM 1024
#define LSEQ 13
#define NTOK 4096
#define NHEAD 16

__device__ __forceinline__ uint16_t f2bf(float x){
  union { float f; uint32_t u; } c; c.f = x;
  uint32_t r = (c.u + 0x7FFFu + ((c.u >> 16) & 1u)) >> 16;
  return (uint16_t)r;
}
__device__ __forceinline__ float bf2f(uint16_t h){
  union { uint32_t u; float f; } c; c.u = ((uint32_t)h) << 16;
  return c.f;
}

__device__ __forceinline__ void async16(const void* g, void* l){
  __builtin_amdgcn_global_load_lds((__attribute__((address_space(1))) void*)(g),
                                   (__attribute__((address_space(3))) void*)(l), 16, 0, 0);
}

// ---------------- conversion kernels ----------------

// all four weight matrices in one dispatch; blockIdx.y selects the matrix
__global__ void convert_W4(const float* __restrict__ Wq, const float* __restrict__ Wk,
                           const float* __restrict__ Wv, const float* __restrict__ Wo,
                           uint16_t* __restrict__ W1q, uint16_t* __restrict__ W1k,
                           uint16_t* __restrict__ W1v, uint16_t* __restrict__ W1o){
  const float* W = (blockIdx.y == 0) ? Wq : (blockIdx.y == 1) ? Wk : (blockIdx.y == 2) ? Wv : Wo;
  uint16_t* W1   = (blockIdx.y == 0) ? W1q : (blockIdx.y == 1) ? W1k : (blockIdx.y == 2) ? W1v : W1o;
  int idx = blockIdx.x * 256 + threadIdx.x;
  int j = idx >> 8;
  int c4 = (idx & 255) * 4;
  float4 v = *(const float4*)(W + (size_t)j * CDIM + c4);
  u16x4 h;
  h.x = f2bf(v.x); h.y = f2bf(v.y); h.z = f2bf(v.z); h.w = f2bf(v.w);
  *(u16x4*)(W1 + (size_t)j * CDIM + c4) = h;
}

__global__ void rope_table(float* __restrict__ cosT, float* __restrict__ sinT){
  int t = threadIdx.x;
  if (t < LSEQ * 32){
    int l = t >> 5, i = t & 31;
    float inv = 1.0f / powf(10000.0f, ((float)(2 * i)) / 64.0f);
    float a = (float)l * inv;
    cosT[t] = cosf(a);
    sinT[t] = sinf(a);
  }
}

// chunk A rows (n_local*13 + l) -> bf16 hi
__global__ void convert_A(const float* __restrict__ src, uint16_t* __restrict__ Ah, int n0){
  int idx = blockIdx.x * 256 + threadIdx.x;
  int row = idx >> 8;
  int c4 = (idx & 255) * 4;
  int nl = row / 13;
  int l  = row - nl * 13;
  float4 v = *(const float4*)(src + (size_t)l * (NTOK * CDIM) + (size_t)(n0 + nl) * CDIM + c4);
  u16x4 h;
  h.x = f2bf(v.x); h.y = f2bf(v.y); h.z = f2bf(v.z); h.w = f2bf(v.w);
  *(u16x4*)(Ah + (size_t)row * CDIM + c4) = h;
}

// Q input rows (l = 12 only) -> bf16 hi  (multi-chunk fallback only)
__global__ void convert_Aq1(const float* __restrict__ src, uint16_t* __restrict__ Ah){
  int idx = blockIdx.x * 256 + threadIdx.x;
  int n = idx >> 8;
  int c4 = (idx & 255) * 4;
  float4 v = *(const float4*)(src + (size_t)12 * (NTOK * CDIM) + (size_t)n * CDIM + c4);
  u16x4 h;
  h.x = f2bf(v.x); h.y = f2bf(v.y); h.z = f2bf(v.z); h.w = f2bf(v.w);
  *(u16x4*)(Ah + (size_t)n * CDIM + c4) = h;
}

// ---------------- 128x128 x1 GEMM template (2-barrier m97 structure) ----------------
// AMODE 0: A row-major stride CDIM. AMODE 1: A in [head][NTOK][64] planes.
template<int AMODE>
__global__ __launch_bounds__(256, 2)
void gemm128(const uint16_t* __restrict__ Ahi, const uint16_t* __restrict__ B1,
             float* __restrict__ Cout)
{
  __shared__ __align__(16) uint16_t sA[128 * 64];
  __shared__ __align__(16) uint16_t sB[128 * 64];
  const int tid  = threadIdx.x;
  const int lane = tid & 63;
  const int wave = tid >> 6;
  const int arow0 = blockIdx.x * 128;
  const int bcol0 = blockIdx.y * 128;
  const int wr = (wave >> 1) * 64;
  const int wc = (wave & 1) * 64;

  const f32x4 fzero = {0.f, 0.f, 0.f, 0.f};
  f32x4 acc[4][4];
#pragma unroll
  for (int i = 0; i < 4; ++i)
#pragma unroll
    for (int j = 0; j < 4; ++j)
      acc[i][j] = fzero;

  size_t aOff[4], bOff[4];
  int ldsOff[4];
#pragma unroll
  for (int i = 0; i < 4; ++i){
    int o = i * 256 + tid;
    int row = o >> 3;
    int ss = (o & 7) ^ (row & 7);
    if (AMODE == 1) aOff[i] = (size_t)(arow0 + row) * 64 + ss * 8;
    else            aOff[i] = (size_t)(arow0 + row) * CDIM + ss * 8;
    bOff[i] = (size_t)(bcol0 + row) * CDIM + ss * 8;
    ldsOff[i] = (i * 256 + wave * 64) * 16;
  }

  int aRd[2][4], bRd[2][4];
#pragma unroll
  for (int ks = 0; ks < 2; ++ks){
    int sw = ((lane >> 4) + ks * 4) ^ (lane & 7);
#pragma unroll
    for (int mi = 0; mi < 4; ++mi){
      aRd[ks][mi] = (wr + mi * 16 + (lane & 15)) * 128 + sw * 16;
      bRd[ks][mi] = (wc + mi * 16 + (lane & 15)) * 128 + sw * 16;
    }
  }

  const char* sAc = (const char*)sA;
  const char* sBc = (const char*)sB;

  for (int step = 0; step < 16; ++step){
    const int kr0 = step * 64;
    const size_t aStep = (AMODE == 1) ? ((size_t)(kr0 >> 6) * (NTOK * 64)) : (size_t)kr0;
#pragma unroll
    for (int i = 0; i < 4; ++i){
      async16(Ahi + aStep + aOff[i], (char*)sA + ldsOff[i]);
      async16(B1 + bOff[i] + kr0, (char*)sB + ldsOff[i]);
    }
    __syncthreads();
#pragma unroll
    for (int ks = 0; ks < 2; ++ks){
      bf16x8 af[4], bfr[4];
#pragma unroll
      for (int mi = 0; mi < 4; ++mi) af[mi]  = *(const bf16x8*)(sAc + aRd[ks][mi]);
#pragma unroll
      for (int ni = 0; ni < 4; ++ni) bfr[ni] = *(const bf16x8*)(sBc + bRd[ks][ni]);
#pragma unroll
      for (int mi = 0; mi < 4; ++mi)
#pragma unroll
        for (int ni = 0; ni < 4; ++ni)
          acc[mi][ni] = __builtin_amdgcn_mfma_f32_16x16x32_bf16(af[mi], bfr[ni], acc[mi][ni], 0, 0, 0);
    }
    __syncthreads();
  }

#pragma unroll
  for (int mi = 0; mi < 4; ++mi){
    const int row = arow0 + wr + mi * 16 + (lane >> 4) * 4;
#pragma unroll
    for (int r = 0; r < 4; ++r){
      float* crow = Cout + (size_t)(row + r) * CDIM + bcol0 + wc + (lane & 15);
#pragma unroll
      for (int ni = 0; ni < 4; ++ni)
        crow[ni * 16] = acc[mi][ni][r];
    }
  }
}

// ---------------- 256x256 8-phase x1 GEMM — fused K projection + Q projection ----------------
__global__ __launch_bounds__(512, 1)
void gemm8_kq(const uint16_t* __restrict__ Ahi, const uint16_t* __restrict__ Bk,
              const uint16_t* __restrict__ Bq, uint16_t* __restrict__ Kout,
              float* __restrict__ Qout, int mtK)
{
  constexpr int NSTEP = 16;
  __shared__ __align__(16) char smem[131072];
  const int tid  = threadIdx.x;
  const int lane = tid & 63;
  const int wave = tid >> 6;
  const int wave_m = wave >> 2;
  const int wave_n = wave & 3;
  const bool isQ = (int)blockIdx.y >= mtK;
  const int arow0 = (isQ ? ((int)blockIdx.y - mtK) : (int)blockIdx.y) * 256;
  const int bcol0 = blockIdx.x * 256;
  const uint16_t* B1 = isQ ? Bq : Bk;

  const f32x4 fzero = {0.f, 0.f, 0.f, 0.f};
  f32x4 acc[8][4];
#pragma unroll
  for (int i = 0; i < 8; ++i)
#pragma unroll
    for (int j = 0; j < 4; ++j)
      acc[i][j] = fzero;

  const int abase0 = (wave_m * 128 + (lane & 15)) * 128;
  const int bbase0 = (wave_n * 64  + (lane & 15)) * 128;
  const int s0 = (((lane >> 4))     ^ (lane & 7)) * 16;
  const int s1 = ((4 + (lane >> 4)) ^ (lane & 7)) * 16;

  size_t aU[2][2], bU[2][2];
  int ldsU[2][2];
#pragma unroll
  for (int h = 0; h < 2; ++h)
#pragma unroll
    for (int j = 0; j < 2; ++j){
      int u = h * 1024 + (wave * 2 + j) * 64 + lane;
      int row = u >> 3;
      int ss = (u & 7) ^ (row & 7);          // pre-swizzled source slot (rule #21)
      aU[h][j] = isQ ? (((size_t)(arow0 + row) * 13 + 12) * CDIM + ss * 8)
                     : ((size_t)(arow0 + row) * CDIM + ss * 8);
      bU[h][j] = (size_t)(bcol0 + row) * CDIM + ss * 8;
      ldsU[h][j] = (h * 1024 + (wave * 2 + j) * 64) * 16;
    }

  auto stA = [&](int h, int tt, int dsel){
    const int k0 = tt * 64;
    async16(Ahi + aU[h][0] + k0, smem + dsel + ldsU[h][0]);
    async16(Ahi + aU[h][1] + k0, smem + dsel + ldsU[h][1]);
  };
  auto stB = [&](int h, int tt, int dsel){
    const int k0 = tt * 64;
    async16(B1 + bU[h][0] + k0, smem + 65536 + dsel + ldsU[h][0]);
    async16(B1 + bU[h][1] + k0, smem + 65536 + dsel + ldsU[h][1]);
  };

#define RDA(dst, M, As) { dst[0] = *(const bf16x8*)((As) + abase0 + (M)*2048 + s0); \
                          dst[1] = *(const bf16x8*)((As) + abase0 + (M)*2048 + s1); }
#define MM(MI, AF) { _Pragma("unroll") for (int n = 0; n < 4; ++n){ \
    acc[MI][n] = __builtin_amdgcn_mfma_f32_16x16x32_bf16(AF[0], bf[n][0], acc[MI][n], 0, 0, 0); \
    acc[MI][n] = __builtin_amdgcn_mfma_f32_16x16x32_bf16(AF[1], bf[n][1], acc[MI][n], 0, 0, 0); } }

  // prologue
  stB(0, 0, 0);     stB(1, 0, 0);     stA(0, 0, 0);     stA(1, 0, 0);
  stB(0, 1, 32768); stB(1, 1, 32768); stA(0, 1, 32768);
  asm volatile("s_waitcnt vmcnt(6)" ::: "memory");
  __builtin_amdgcn_sched_barrier(0);
  __builtin_amdgcn_s_barrier();

#pragma unroll 2
  for (int t = 0; t < NSTEP; ++t){
    const int sel  = (t & 1) * 32768;
    const int seln = 32768 - sel;
    const char* As = smem + sel;
    const char* Bs = smem + 65536 + sel;

    bf16x8 bf[4][2], a0[2], a1[2], a2[2], a3[2], a4[2], a5[2], a6[2], a7[2];

    // phase 0
#pragma unroll
    for (int n = 0; n < 4; ++n){
      bf[n][0] = *(const bf16x8*)(Bs + bbase0 + n * 2048 + s0);
      bf[n][1] = *(const bf16x8*)(Bs + bbase0 + n * 2048 + s1);
    }
    RDA(a0, 0, As); RDA(a1, 1, As);
    if (t + 1 < NSTEP) stA(1, t + 1, seln);
    __builtin_amdgcn_s_barrier();
    __builtin_amdgcn_s_setprio(1);
    MM(0, a0); MM(1, a1);
    __builtin_amdgcn_s_setprio(0);
    __builtin_amdgcn_s_barrier();

    // phase 1
    RDA(a2, 2, As); RDA(a3, 3, As); RDA(a4, 4, As); RDA(a5, 5, As);
    if (t + 2 < NSTEP) stB(0, t + 2, sel);
    __builtin_amdgcn_s_barrier();
    __builtin_amdgcn_s_setprio(1);
    MM(2, a2); MM(3, a3);
    __builtin_amdgcn_s_setprio(0);
    __builtin_amdgcn_s_barrier();

    // phase 2
    RDA(a6, 6, As); RDA(a7, 7, As);
    if (t + 2 < NSTEP) stB(1, t + 2, sel);
    __builtin_amdgcn_s_barrier();
    __builtin_amdgcn_s_setprio(1);
    MM(4, a4); MM(5, a5);
    __builtin_amdgcn_s_setprio(0);
    asm volatile("s_waitcnt lgkmcnt(0)" ::: "memory");
    __builtin_amdgcn_sched_barrier(0);
    __builtin_amdgcn_s_barrier();

    // phase 3
    if (t + 2 < NSTEP) stA(0, t + 2, sel);
    if (t <= NSTEP - 3) { asm volatile("s_waitcnt vmcnt(6)" ::: "memory"); }
    else                { asm volatile("s_waitcnt vmcnt(0)" ::: "memory"); }
    __builtin_amdgcn_sched_barrier(0);
    __builtin_amdgcn_s_barrier();
    __builtin_amdgcn_s_setprio(1);
    MM(6, a6); MM(7, a7);
    __builtin_amdgcn_s_setprio(0);
    __builtin_amdgcn_s_barrier();
  }
#undef RDA
#undef MM

#pragma unroll
  for (int mi = 0; mi < 8; ++mi){
    const int row = arow0 + wave_m * 128 + mi * 16 + (lane >> 4) * 4;
#pragma unroll
    for (int r = 0; r < 4; ++r){
      const size_t co = (size_t)(row + r) * CDIM + bcol0 + wave_n * 64 + (lane & 15);
      if (isQ){
        float* crow = Qout + co;
#pragma unroll
        for (int ni = 0; ni < 4; ++ni)
          crow[ni * 16] = acc[mi][ni][r];
      } else {
        uint16_t* crow = Kout + co;
#pragma unroll
        for (int ni = 0; ni < 4; ++ni)
          crow[ni * 16] = f2bf(acc[mi][ni][r]);
      }
    }
  }
}

// ---------------- fused RoPE scores + mix: MIX[h][n][c] = sum_m p[m] * seq[n,m,c] ----------------
// Phase 1 (wave = head): scores -> sP[13][16].
// Phase 2 (thread = column; R15 proven form): thread owns col c = tid; converts seq[m][c]
// once, 16 FMAs via broadcast p (conflict-free 2B LDS reads).
__global__ __launch_bounds__(1024)
void attnmix(const uint16_t* __restrict__ Kb, const uint16_t* __restrict__ Ah,
             const float* __restrict__ q, const float* __restrict__ cosT,
             const float* __restrict__ sinT, uint16_t* __restrict__ MIX, int n0)
{
  __shared__ __align__(16) uint16_t sSeq[LSEQ * CDIM];   // 26 KB
  __shared__ __align__(16) float sP[LSEQ][NHEAD];
  const int tid  = threadIdx.x;
  const int lane = tid & 63;
  const int h    = tid >> 6;
  const int nl   = blockIdx.x;
  const int n    = n0 + nl;
  const int d = lane, i = d & 31;

  const uint16_t* Abase = Ah + (size_t)nl * (LSEQ * CDIM);
  {
    async16(Abase + (size_t)tid * 8, (char*)sSeq + (tid - lane) * 16);
    int u1 = 1024 + tid;
    if (u1 < LSEQ * 128)
      async16(Abase + (size_t)u1 * 8, (char*)sSeq + (1024 + tid - lane) * 16);
  }

  float qv = q[(size_t)n * CDIM + h * 64 + d];
  float qp = __shfl_xor(qv, 32);
  float cq = cosT[12 * 32 + i], sq = sinT[12 * 32 + i];
  float qr = (d < 32) ? (qv * cq - qp * sq) : (qv * cq + qp * sq);

  const uint16_t* Kp = Kb + (size_t)nl * (LSEQ * CDIM) + h * 64 + d;
  float s[LSEQ];
#pragma unroll
  for (int m = 0; m < LSEQ; ++m){
    float kv = bf2f(Kp[m * CDIM]);
    float kp = __shfl_xor(kv, 32);
    float cm = cosT[m * 32 + i], sm = sinT[m * 32 + i];
    float kr = (d < 32) ? (kv * cm - kp * sm) : (kv * cm + kp * sm);
    float p = qr * kr;
    p += __shfl_xor(p, 32); p += __shfl_xor(p, 16); p += __shfl_xor(p, 8);
    p += __shfl_xor(p, 4);  p += __shfl_xor(p, 2);  p += __shfl_xor(p, 1);
    s[m] = p * 0.125f;
  }
  float mx = s[0];
#pragma unroll
  for (int m = 1; m < LSEQ; ++m) mx = fmaxf(mx, s[m]);
  float sum = 0.f;
#pragma unroll
  for (int m = 0; m < LSEQ; ++m){ s[m] = expf(s[m] - mx); sum += s[m]; }
  float inv = 1.0f / sum;
#pragma unroll
  for (int m = 0; m < LSEQ; ++m) s[m] *= inv;

  if (lane == 0){
#pragma unroll
    for (int m = 0; m < LSEQ; ++m) sP[m][h] = s[m];
  }

  __syncthreads();   // seq staged (drains vmcnt) + sP published

  float ac[NHEAD];
#pragma unroll
  for (int k = 0; k < NHEAD; ++k) ac[k] = 0.f;
#pragma unroll
  for (int m = 0; m < LSEQ; ++m){
    float v = bf2f(sSeq[m * CDIM + tid]);
    const f32x4 p0 = *(const f32x4*)&sP[m][0];
    const f32x4 p1 = *(const f32x4*)&sP[m][4];
    const f32x4 p2 = *(const f32x4*)&sP[m][8];
    const f32x4 p3 = *(const f32x4*)&sP[m][12];
    ac[0]  += p0.x * v; ac[1]  += p0.y * v; ac[2]  += p0.z * v; ac[3]  += p0.w * v;
    ac[4]  += p1.x * v; ac[5]  += p1.y * v; ac[6]  += p1.z * v; ac[7]  += p1.w * v;
    ac[8]  += p2.x * v; ac[9]  += p2.y * v; ac[10] += p2.z * v; ac[11] += p2.w * v;
    ac[12] += p3.x * v; ac[13] += p3.y * v; ac[14] += p3.z * v; ac[15] += p3.w * v;
  }
#pragma unroll
  for (int k = 0; k < NHEAD; ++k)
    MIX[((size_t)k * NTOK + n) * CDIM + tid] = f2bf(ac[k]);
}

// ---------------- per-head GEMM: t1[h][n][d] = MIX[h][n][:] . Wv[h*64+d][:] (bf16 out) ----------------
__global__ __launch_bounds__(256, 2)
void hd_gemm(const uint16_t* __restrict__ MIX, const uint16_t* __restrict__ Wv,
             uint16_t* __restrict__ t1h)
{
  __shared__ __align__(16) uint16_t sA[256 * 64];
  __shared__ __align__(16) uint16_t sB[64 * 64];
  const int tid  = threadIdx.x;
  const int lane = tid & 63;
  const int wave = tid >> 6;
  const int h     = blockIdx.y;
  const int arow0 = blockIdx.x * 256;
  const uint16_t* Aplane = MIX + (size_t)h * ((size_t)NTOK * CDIM);
  const uint16_t* Bbase  = Wv + (size_t)h * 64 * CDIM;

  const f32x4 fzero = {0.f, 0.f, 0.f, 0.f};
  f32x4 acc[4][4];
#pragma unroll
  for (int i = 0; i < 4; ++i)
#pragma unroll
    for (int j = 0; j < 4; ++j)
      acc[i][j] = fzero;

  size_t aOff[8]; int aLds[8];
#pragma unroll
  for (int i = 0; i < 8; ++i){
    int u = i * 256 + tid;
    int row = u >> 3;
    int ss = (u & 7) ^ (row & 7);
    aOff[i] = (size_t)(arow0 + row) * CDIM + ss * 8;
    aLds[i] = (i * 256 + wave * 64) * 16;
  }
  size_t bOff[2]; int bLds[2];
#pragma unroll
  for (int i = 0; i < 2; ++i){
    int u = i * 256 + tid;
    int row = u >> 3;
    int ss = (u & 7) ^ (row & 7);
    bOff[i] = (size_t)row * CDIM + ss * 8;
    bLds[i] = (i * 256 + wave * 64) * 16;
  }

  int aRd[2][4], bRd[2][4];
#pragma unroll
  for (int ks = 0; ks < 2; ++ks){
    int sw = ((lane >> 4) + ks * 4) ^ (lane & 7);
#pragma unroll
    for (int mi = 0; mi < 4; ++mi){
      aRd[ks][mi] = (wave * 64 + mi * 16 + (lane & 15)) * 128 + sw * 16;
      bRd[ks][mi] = (mi * 16 + (lane & 15)) * 128 + sw * 16;
    }
  }

  const char* sAc = (const char*)sA;
  const char* sBc = (const char*)sB;

  for (int step = 0; step < 16; ++step){
    const int k0 = step * 64;
#pragma unroll
    for (int i = 0; i < 8; ++i)
      async16(Aplane + aOff[i] + k0, (char*)sA + aLds[i]);
#pragma unroll
    for (int i = 0; i < 2; ++i)
      async16(Bbase + bOff[i] + k0, (char*)sB + bLds[i]);
    __syncthreads();
#pragma unroll
    for (int ks = 0; ks < 2; ++ks){
      bf16x8 af[4], bfr[4];
#pragma unroll
      for (int mi = 0; mi < 4; ++mi) af[mi]  = *(const bf16x8*)(sAc + aRd[ks][mi]);
#pragma unroll
      for (int ni = 0; ni < 4; ++ni) bfr[ni] = *(const bf16x8*)(sBc + bRd[ks][ni]);
#pragma unroll
      for (int mi = 0; mi < 4; ++mi)
#pragma unroll
        for (int ni = 0; ni < 4; ++ni)
          acc[mi][ni] = __builtin_amdgcn_mfma_f32_16x16x32_bf16(af[mi], bfr[ni], acc[mi][ni], 0, 0, 0);
    }
    __syncthreads();
  }

#pragma unroll
  for (int mi = 0; mi < 4; ++mi){
    const int row = arow0 + wave * 64 + mi * 16 + (lane >> 4) * 4;
#pragma unroll
    for (int r = 0; r < 4; ++r){
      const size_t base = ((size_t)h * NTOK + row + r) * 64 + (lane & 15);
#pragma unroll
      for (int ni = 0; ni < 4; ++ni)
        t1h[base + ni * 16] = f2bf(acc[mi][ni][r]);
    }
  }
}

// ---------------- host ----------------
extern "C" void kernel_launch(void* const* d_in, const int* in_sizes, int n_in,
                              void* d_out, int out_size, void* d_ws, size_t ws_size,
                              hipStream_t stream)
{
  (void)in_sizes; (void)n_in; (void)out_size;
  const float* src = (const float*)d_in[0];
  const float* Wq  = (const float*)d_in[1];
  const float* Wk  = (const float*)d_in[2];
  const float* Wv  = (const float*)d_in[3];
  const float* Wo  = (const float*)d_in[4];
  float* out = (float*)d_out;

  int cn = 4096;
  while (cn > 256 && (180000000ull + (size_t)cn * 53248ull) > ws_size) cn >>= 1;
  const int nchunks = NTOK / cn;

  char* p = (char*)d_ws;
  auto carve = [&](size_t bytes) -> void* {
    void* r = (void*)p; p += (bytes + 255) & ~(size_t)255; return r;
  };
  uint16_t* W1q = (uint16_t*)carve((size_t)CDIM * CDIM * 2);
  uint16_t* W1k = (uint16_t*)carve((size_t)CDIM * CDIM * 2);
  uint16_t* W1v = (uint16_t*)carve((size_t)CDIM * CDIM * 2);
  uint16_t* W1o = (uint16_t*)carve((size_t)CDIM * CDIM * 2);
  float* cosT = (float*)carve(LSEQ * 32 * 4);
  float* sinT = (float*)carve(LSEQ * 32 * 4);
  uint16_t* Aqh = (uint16_t*)carve((size_t)NTOK * CDIM * 2);   // multi-chunk fallback only
  float* qbuf   = (float*)carve((size_t)NTOK * CDIM * 4);
  uint16_t* MIX = (uint16_t*)carve((size_t)NHEAD * NTOK * CDIM * 2);   // 134 MB
  uint16_t* t1h = (uint16_t*)carve((size_t)NHEAD * NTOK * 64 * 2);
  uint16_t* Ah  = (uint16_t*)carve((size_t)cn * LSEQ * CDIM * 2);
  uint16_t* Kb  = (uint16_t*)carve((size_t)cn * LSEQ * CDIM * 2);

  convert_W4<<<dim3(1024, 4), 256, 0, stream>>>(Wq, Wk, Wv, Wo, W1q, W1k, W1v, W1o);
  rope_table<<<1, 512, 0, stream>>>(cosT, sinT);

  if (nchunks > 1){
    convert_Aq1<<<NTOK, 256, 0, stream>>>(src, Aqh);
    gemm128<0><<<dim3(NTOK / 128, 8), 256, 0, stream>>>(Aqh, W1q, qbuf);
  }

  for (int c = 0; c < nchunks; ++c){
    const int mtK = cn * LSEQ / 256;
    const int mtQ = (nchunks == 1) ? (NTOK / 256) : 0;   // fold Q tiles into the K dispatch
    convert_A<<<cn * LSEQ, 256, 0, stream>>>(src, Ah, c * cn);
    gemm8_kq<<<dim3(4, mtK + mtQ), 512, 0, stream>>>(Ah, W1k, W1q, Kb, qbuf, mtK);
    attnmix<<<cn, 1024, 0, stream>>>(Kb, Ah, qbuf, cosT, sinT, MIX, c * cn);
  }
  hd_gemm<<<dim3(16, 16), 256, 0, stream>>>(MIX, W1v, t1h);
  gemm128<1><<<dim3(NTOK / 128, 8), 256, 0, stream>>>(t1h, W1o, out);
}